// Round 14
// baseline (9839.796 us; speedup 1.0000x reference)
//
#include <hip/hip_runtime.h>
#include <math.h>

#define NB 64      // batch
#define NH 512     // hidden
#define NV 64      // vocab
#define NT 200     // T
#define NSTEP 199
#define GBLK 128   // main-loop blocks (4 cells / 16 gate rows each)
#define GTHR 512   // threads per block

#define RLX   __ATOMIC_RELAXED
#define AGENT __HIP_MEMORY_SCOPE_AGENT

typedef float f4v __attribute__((ext_vector_type(4)));

// ---------------- threefry / gumbel --------------------------------------
// jax.random.categorical(jax.random.key(1),...) with jax_threefry_partitionable=True:
// bits = x0^x1 of threefry2x32(key=(0,1), counter=(0, flat_index))
__device__ inline float gumbel_tf(unsigned f){
  const unsigned ksc[3] = {0u, 1u, 0x1BD11BDBu};
  unsigned x0 = 0u + ksc[0];
  unsigned x1 = f  + ksc[1];
  const int R0[4] = {13,15,26,6};
  const int R1[4] = {17,29,16,24};
  #pragma unroll
  for (int i = 0; i < 5; ++i){
    #pragma unroll
    for (int r = 0; r < 4; ++r){
      int rot = (i & 1) ? R1[r] : R0[r];
      x0 += x1;
      x1 = (x1 << rot) | (x1 >> (32 - rot));
      x1 ^= x0;
    }
    x0 += ksc[(i+1)%3];
    x1 += ksc[(i+2)%3] + (unsigned)(i+1);
  }
  unsigned bits = x0 ^ x1;
  float u = __uint_as_float((bits >> 9) | 0x3F800000u) - 1.0f;
  u = fmaxf(u, 1.17549435e-38f);
  return -logf(-logf(u));
}

__device__ inline float sigf(float x){ return 1.0f/(1.0f + expf(-x)); }

// ---------------- all-poll grid barrier ----------------
// Monotone per-block flags (64B-strided). Arrival: returning agent-scope
// atomic exchange after per-wave vmcnt drain + block sync (R3/R8-proven
// discipline). Wait: 128 threads each poll one flag; no collector.
__device__ inline void gbar_wait(unsigned* flags, unsigned tgt){
  if (threadIdx.x < GBLK){
    while (__hip_atomic_load(&flags[threadIdx.x*16], RLX, AGENT) < tgt){
      __builtin_amdgcn_s_sleep(1);
    }
  }
  __syncthreads();
}

// ---------------- block reductions (verbatim R8) ----------------
__device__ inline float blk_red_max(float v, float* scr){
  #pragma unroll
  for (int m = 1; m < 64; m <<= 1) v = fmaxf(v, __shfl_xor(v, m, 64));
  if ((threadIdx.x & 63) == 0) scr[threadIdx.x >> 6] = v;
  __syncthreads();
  float r = scr[0];
  #pragma unroll
  for (int i = 1; i < 8; ++i) r = fmaxf(r, scr[i]);
  __syncthreads();
  return r;
}
__device__ inline float blk_red_sum(float v, float* scr){
  #pragma unroll
  for (int m = 1; m < 64; m <<= 1) v += __shfl_xor(v, m, 64);
  if ((threadIdx.x & 63) == 0) scr[threadIdx.x >> 6] = v;
  __syncthreads();
  float r = 0.f;
  #pragma unroll
  for (int i = 0; i < 8; ++i) r += scr[i];
  __syncthreads();
  return r;
}

// ---------------- precompute kernels (verbatim R8) -----------
__global__ void k_msum_part(const float* __restrict__ emb, const int* __restrict__ lens,
                            float* __restrict__ part){
  int blk = blockIdx.x, b = blk >> 3, lc = blk & 7;
  int len = lens[b];
  int l0 = lc*64, l1 = len < l0+64 ? len : l0+64;
  for (int h = threadIdx.x; h < 512; h += 256){
    float a = 0.f;
    for (int l = l0; l < l1; ++l) a += emb[(b*512 + l)*512 + h];
    part[blk*512 + h] = a;
  }
}
__global__ void k_msum(const float* __restrict__ part, float* __restrict__ msumT){
  int b = blockIdx.x;
  for (int h = threadIdx.x; h < 512; h += 256){
    float a = 0.f;
    #pragma unroll
    for (int lc = 0; lc < 8; ++lc) a += part[(b*8+lc)*512 + h];
    msumT[h*64 + b] = a;
  }
}
__global__ void k_kv(const float* __restrict__ msumT,
                     const float* __restrict__ kw, const float* __restrict__ kb,
                     const float* __restrict__ vw, const float* __restrict__ vb,
                     float* __restrict__ keysum, float* __restrict__ valsum){
  int which = blockIdx.x >> 7;
  int i = ((blockIdx.x & 127) << 2) + (threadIdx.x >> 6);
  int b = threadIdx.x & 63;
  const float* W = which ? vw : kw;
  float a = 0.f;
  for (int h = 0; h < 512; ++h) a = fmaf(msumT[h*64+b], W[i*512+h], a);
  float bias = which ? vb[i] : kb[i];
  float* out = which ? valsum : keysum;
  out[b*512 + i] = a + 512.0f*bias;
}
__global__ void k_ceT(const float* __restrict__ ce, float* __restrict__ ceT){
  int idx = blockIdx.x*256 + threadIdx.x;
  if (idx < 32768){ int v = idx >> 9, e = idx & 511; ceT[e*64 + v] = ce[v*512 + e]; }
}
__global__ void k_tok(const float* __restrict__ ceT, const float* __restrict__ w_ih,
                      const float* __restrict__ b_ih, const float* __restrict__ b_hh,
                      float* __restrict__ tok){
  int idx = blockIdx.x*256 + threadIdx.x;
  int v = idx & 63, row = idx >> 6;
  float a = 0.f;
  for (int e = 0; e < 512; ++e) a = fmaf(ceT[e*64+v], w_ih[row*1024 + e], a);
  tok[v*2048 + row] = a + b_ih[row] + b_hh[row];
}
// cdnT transpose, x slot0 init (ctx0 = valsum/512, hh0 = 0), t=0 outputs, barrier zeroing
__global__ void k_init(const float* __restrict__ valsum, const float* __restrict__ cdn_w,
                       float* __restrict__ cdnT, float* __restrict__ xT,
                       float* __restrict__ out, unsigned* __restrict__ bar){
  int idx = blockIdx.x*256 + threadIdx.x;
  if (idx < 65536){
    int v = idx >> 10, k = idx & 1023;
    cdnT[k*64 + v] = cdn_w[idx];
  } else if (idx < 98304){
    int r = idx - 65536; int j = r >> 6, b = r & 63;
    xT[j*64 + b] = valsum[b*512 + j] * (1.0f/512.0f);
  } else if (idx < 131072){
    xT[idx - 65536] = 0.f;
  } else if (idx < 135168){
    int r = idx - 131072; int b = r >> 6, v = r & 63;
    out[b*12800 + v] = 0.f;
  } else if (idx < 135232){
    int b = idx - 135168;
    out[819200 + b*200] = 0.f;
  } else if (idx < 139392){
    bar[idx - 135232] = 0u;   // flags region
  }
}

// ---------------- dynamic-LDS layout (107 KB) ----------------
struct Smem {
  float W[1024][16];     // [k][r], r = gate*4 + cell   (64 KB)
  float red[8][16][64];  // [wave][r][b]                (32 KB)
  float gates[16][64];
  float cc[4][64];
  float pb_h[512];
  float pb_c[512];
  float pb_lp[8][64];
  float scr[8];
};

// ---------------- main persistent loop kernel ----------------
// 128 blocks x 512 thr, 4 cells (16 gate rows) per block. Per-(row,batch) FP
// sequence is VERBATIM R8/R12 (R12 passed bit-identical). Changes vs R13:
//  (1) depth-8 rolling load pipeline (A0..A7, WAITV(7)) — halves in-flight
//      VGPRs (64->32) so demand fits under 128 even worst-case;
//  (2) amdgpu_waves_per_eu(2,2) — tells the backend exactly 2 waves/EU (the
//      floor forced by one resident 512-thread block), releasing the 256-VGPR
//      budget that the dynamic-LDS-blind heuristic was withholding (R12/R13
//      spilled the pipeline regs: 15 MB/step scratch writes).
// Load-order-only change: CMP sequence (jj=0..31) untouched -> FP-identical.
__global__ __launch_bounds__(GTHR) __attribute__((amdgpu_waves_per_eu(2,2)))
void k_loop(
    const float* __restrict__ w_ih, const float* __restrict__ w_hh,
    const int* __restrict__ batch_y, const float* __restrict__ tok,
    const float* __restrict__ keysum, const float* __restrict__ valsum,
    const float* __restrict__ cdnT, const float* __restrict__ cdn_b,
    float* __restrict__ xT, float* __restrict__ out,
    unsigned* __restrict__ flags){
  extern __shared__ char smem_raw[];
  Smem& S = *reinterpret_cast<Smem*>(smem_raw);

  const int tid = threadIdx.x;
  const int blk = blockIdx.x;
  const bool HASB = (blk < 64);

  // stage weights: S.W[k][r], r = g*4 + c, row = g*512 + blk*4 + c
  for (int idx = tid; idx < 16384; idx += GTHR){
    int k = idx >> 4, r = idx & 15;
    int g = r >> 2, c = r & 3;
    int row = g*512 + blk*4 + c;
    S.W[k][r] = (k < 512) ? w_ih[row*1024 + 512 + k] : w_hh[row*512 + (k - 512)];
  }
  if (tid < 256) S.cc[tid >> 6][tid & 63] = 0.0f;
  __syncthreads();

  const int w = tid >> 6, l = tid & 63, kg = l >> 4, bg = l & 15;
  const float SCALE = 22.627416997969522f;   // sqrt(512)
  int p = 0;

#define ISS1(R, JJ) do{ const float* _p = xin + (((kbase + (JJ)*4) << 6) | (bg << 2)); \
  asm volatile("global_load_dwordx4 %0, %1, off sc0 sc1" : "=v"(R) : "v"(_p)); }while(0)
#define CMP1(R, JJ) do{ int _k = kbase + (JJ)*4; \
  f4v _wA = *(const f4v*)&S.W[_k][0];  f4v _wB = *(const f4v*)&S.W[_k][4]; \
  f4v _wC = *(const f4v*)&S.W[_k][8];  f4v _wD = *(const f4v*)&S.W[_k][12]; \
  float _wv[16] = {_wA.x,_wA.y,_wA.z,_wA.w,_wB.x,_wB.y,_wB.z,_wB.w, \
                   _wC.x,_wC.y,_wC.z,_wC.w,_wD.x,_wD.y,_wD.z,_wD.w}; \
  float _xv[4] = {R.x,R.y,R.z,R.w}; \
  _Pragma("unroll") for (int _r = 0; _r < 16; ++_r){ \
    _Pragma("unroll") for (int _q = 0; _q < 4; ++_q) \
      acc[_r][_q] = fmaf(_wv[_r], _xv[_q], acc[_r][_q]); } }while(0)
#define WAITV(N) do{ asm volatile("s_waitcnt vmcnt(" #N ")" ::: "memory"); \
  __builtin_amdgcn_sched_barrier(0); }while(0)
#define PSTEP(R, JJ) do{ WAITV(7); CMP1(R,(JJ)); ISS1(R,(JJ)+8); }while(0)

  for (int s = 0; s < NSTEP; ++s){
    const float* xin  = xT + p*65536;
    float*       xout = xT + (p^1)*65536;
    const unsigned t1 = (unsigned)(2*s + 1), t2 = (unsigned)(2*s + 2);

    // prefetch token-gate values (two rows per thread; L2-hot normal loads)
    const int rr = tid >> 6, rb = tid & 63;
    int yprev = (s == 0) ? 0 : batch_y[rb*200 + s];
    float tok1 = tok[yprev*2048 + (rr >> 2)*512 + blk*4 + (rr & 3)];
    float tok2 = tok[yprev*2048 + ((rr + 8) >> 2)*512 + blk*4 + ((rr + 8) & 3)];

    // ---- Phase A: gates via depth-8 rolling counted-vmcnt pipeline ----
    float acc[16][4];
    #pragma unroll
    for (int r = 0; r < 16; ++r)
      #pragma unroll
      for (int q = 0; q < 4; ++q) acc[r][q] = 0.f;

    const int kbase = w*128 + kg;
    {
      f4v A0,A1,A2,A3,A4,A5,A6,A7;
      ISS1(A0,0); ISS1(A1,1); ISS1(A2,2); ISS1(A3,3);
      ISS1(A4,4); ISS1(A5,5); ISS1(A6,6); ISS1(A7,7);
      PSTEP(A0,0);  PSTEP(A1,1);  PSTEP(A2,2);  PSTEP(A3,3);
      PSTEP(A4,4);  PSTEP(A5,5);  PSTEP(A6,6);  PSTEP(A7,7);
      PSTEP(A0,8);  PSTEP(A1,9);  PSTEP(A2,10); PSTEP(A3,11);
      PSTEP(A4,12); PSTEP(A5,13); PSTEP(A6,14); PSTEP(A7,15);
      PSTEP(A0,16); PSTEP(A1,17); PSTEP(A2,18); PSTEP(A3,19);
      PSTEP(A4,20); PSTEP(A5,21); PSTEP(A6,22); PSTEP(A7,23);
      WAITV(7); CMP1(A0,24);
      WAITV(6); CMP1(A1,25);
      WAITV(5); CMP1(A2,26);
      WAITV(4); CMP1(A3,27);
      WAITV(3); CMP1(A4,28);
      WAITV(2); CMP1(A5,29);
      WAITV(1); CMP1(A6,30);
      WAITV(0); CMP1(A7,31);
    }

    // reduce across kg (lanes ^16, ^32) — tree verbatim R8 per accumulator
    #pragma unroll
    for (int r = 0; r < 16; ++r)
      #pragma unroll
      for (int q = 0; q < 4; ++q){
        float v = acc[r][q];
        v += __shfl_xor(v, 16, 64);
        v += __shfl_xor(v, 32, 64);
        acc[r][q] = v;
      }
    if (l < 16){
      #pragma unroll
      for (int r = 0; r < 16; ++r)
        *(float4*)&S.red[w][r][bg*4] = make_float4(acc[r][0], acc[r][1], acc[r][2], acc[r][3]);
    }
    __syncthreads();
    {
      // assembly: two rows per thread; sum order Σ ww=0..7 verbatim R8
      float g1 = 0.f, g2 = 0.f;
      #pragma unroll
      for (int ww = 0; ww < 8; ++ww){
        g1 += S.red[ww][rr][rb];
        g2 += S.red[ww][rr + 8][rb];
      }
      S.gates[rr][rb]     = g1 + tok1;
      S.gates[rr + 8][rb] = g2 + tok2;
    }
    __syncthreads();
    if (tid < 256){
      int c = tid >> 6, b = tid & 63;
      float ig = S.gates[0  + c][b];
      float fg = S.gates[4  + c][b];
      float gg = S.gates[8  + c][b];
      float og = S.gates[12 + c][b];
      float cprev = S.cc[c][b];
      float cnew = sigf(fg)*cprev + sigf(ig)*tanhf(gg);
      float hnew = sigf(og)*tanhf(cnew);
      S.cc[c][b] = cnew;
      float oldh = __hip_atomic_exchange(&xout[(512 + blk*4 + c)*64 + b], hnew, RLX, AGENT);
      asm volatile("" :: "v"(oldh));
    }

    // ---- barrier 1 arrival (all); only Phase-B blocks wait ----
    asm volatile("s_waitcnt vmcnt(0)" ::: "memory");
    __syncthreads();
    if (tid == 0){
      unsigned o = __hip_atomic_exchange(&flags[blk*16], HASB ? t1 : t2, RLX, AGENT);
      asm volatile("" :: "v"(o));
    }

    if (HASB){
      gbar_wait(flags, t1);

      // ---- Phase B: attend + logits + sampling (verbatim R8) ----
      int b = blk;
      int jj = tid;
      float h = __hip_atomic_load(&xout[(512 + jj)*64 + b], RLX, AGENT);
      S.pb_h[jj] = h;
      float sc = (keysum[b*512 + jj] * h) / SCALE;
      float m = blk_red_max(sc, S.scr);
      float e = expf(sc - m);
      float Ssum = blk_red_sum(e, S.scr);
      float cx = valsum[b*512 + jj] * (e / Ssum);
      S.pb_c[jj] = cx;
      float oldc = __hip_atomic_exchange(&xout[jj*64 + b], cx, RLX, AGENT);
      asm volatile("" :: "v"(oldc));
      __syncthreads();
      int kq = tid >> 6, v = tid & 63;
      float part = 0.f;
      for (int k = kq*128; k < kq*128 + 128; ++k){
        float xh = (k < 512) ? S.pb_h[k] : S.pb_c[k - 512];
        part = fmaf(cdnT[k*64 + v], xh, part);
      }
      S.pb_lp[kq][v] = part;
      __syncthreads();
      if (tid < 64){
        int v2 = tid;
        float logit = cdn_b[v2];
        #pragma unroll
        for (int q = 0; q < 8; ++q) logit += S.pb_lp[q][v2];
        out[b*12800 + (s+1)*64 + v2] = logit;
        float z = gumbel_tf((unsigned)((b*199 + s)*64 + v2)) + logit;
        int idx = v2;
        #pragma unroll
        for (int mm = 1; mm < 64; mm <<= 1){
          float oz = __shfl_xor(z, mm, 64);
          int   oi = __shfl_xor(idx, mm, 64);
          if (oz > z || (oz == z && oi < idx)){ z = oz; idx = oi; }
        }
        if (v2 == 0) out[819200 + b*200 + (s+1)] = (float)idx;
      }

      // barrier 2 arrival for Phase-B blocks
      asm volatile("s_waitcnt vmcnt(0)" ::: "memory");
      __syncthreads();
      if (tid == 0){
        unsigned o = __hip_atomic_exchange(&flags[blk*16], t2, RLX, AGENT);
        asm volatile("" :: "v"(o));
      }
    }

    // ---- barrier 2 wait (all blocks) ----
    gbar_wait(flags, t2);
    p ^= 1;
  }
#undef ISS1
#undef CMP1
#undef WAITV
#undef PSTEP
}

// ---------------- launcher ----------------
extern "C" void kernel_launch(void* const* d_in, const int* in_sizes, int n_in,
                              void* d_out, int out_size, void* d_ws, size_t ws_size,
                              hipStream_t stream){
  const float* seq     = (const float*)d_in[0];
  const float* key_w   = (const float*)d_in[1];
  const float* key_b   = (const float*)d_in[2];
  const float* value_w = (const float*)d_in[3];
  const float* value_b = (const float*)d_in[4];
  const float* char_e  = (const float*)d_in[5];
  const float* w_ih    = (const float*)d_in[6];
  const float* w_hh    = (const float*)d_in[7];
  const float* b_ih    = (const float*)d_in[8];
  const float* b_hh    = (const float*)d_in[9];
  const float* cdn_w   = (const float*)d_in[10];
  const float* cdn_b   = (const float*)d_in[11];
  const int*   lens    = (const int*)d_in[12];
  const int*   batch_y = (const int*)d_in[13];
  float* out = (float*)d_out;
  float* ws  = (float*)d_ws;

  float* msum_part = ws;              // 262144 (precompute only)
  float* msumT     = ws + 262144;     // 32768   [h][b]
  float* keysum    = ws + 294912;     // 32768   [b][i]
  float* valsum    = ws + 327680;     // 32768   [b][i]
  float* tok       = ws + 360448;     // 131072  [v][row]
  float* cdnT      = ws + 491520;     // 65536   [k][v]
  float* ceT       = ws + 557056;     // 32768   [e][v]
  float* xT        = ws + 589824;     // 131072  2 x [k][b] ping-pong
  unsigned* bar    = (unsigned*)(ws + 720896); // flags (64B-strided)

  hipFuncSetAttribute((const void*)k_loop,
                      hipFuncAttributeMaxDynamicSharedMemorySize,
                      (int)sizeof(Smem));

  k_msum_part<<<512, 256, 0, stream>>>(seq, lens, msum_part);
  k_msum     <<<64,  256, 0, stream>>>(msum_part, msumT);
  k_kv       <<<256, 256, 0, stream>>>(msumT, key_w, key_b, value_w, value_b, keysum, valsum);
  k_ceT      <<<128, 256, 0, stream>>>(char_e, ceT);
  k_tok      <<<512, 256, 0, stream>>>(ceT, w_ih, b_ih, b_hh, tok);
  k_init     <<<545, 256, 0, stream>>>(valsum, cdn_w, cdnT, xT, out, bar);

  k_loop<<<GBLK, GTHR, sizeof(Smem), stream>>>(w_ih, w_hh, batch_y, tok, keysum, valsum,
                                               cdnT, cdn_b, xT, out, bar);
  (void)in_sizes; (void)n_in; (void)out_size; (void)ws_size;
}

// Round 15
// 5922.382 us; speedup vs baseline: 1.6615x; 1.6615x over previous
//
#include <hip/hip_runtime.h>
#include <math.h>

#define NB 64      // batch
#define NH 512     // hidden
#define NV 64      // vocab
#define NT 200     // T
#define NSTEP 199
#define GBLK 256   // main-loop blocks
#define GTHR 512   // threads per block

#define RLX   __ATOMIC_RELAXED
#define AGENT __HIP_MEMORY_SCOPE_AGENT
#define WGRP  __HIP_MEMORY_SCOPE_WORKGROUP

typedef float f4v __attribute__((ext_vector_type(4)));

// ---------------- threefry / gumbel --------------------------------------
// jax.random.categorical(jax.random.key(1),...) with jax_threefry_partitionable=True:
// bits = x0^x1 of threefry2x32(key=(0,1), counter=(0, flat_index))
__device__ inline float gumbel_tf(unsigned f){
  const unsigned ksc[3] = {0u, 1u, 0x1BD11BDBu};
  unsigned x0 = 0u + ksc[0];
  unsigned x1 = f  + ksc[1];
  const int R0[4] = {13,15,26,6};
  const int R1[4] = {17,29,16,24};
  #pragma unroll
  for (int i = 0; i < 5; ++i){
    #pragma unroll
    for (int r = 0; r < 4; ++r){
      int rot = (i & 1) ? R1[r] : R0[r];
      x0 += x1;
      x1 = (x1 << rot) | (x1 >> (32 - rot));
      x1 ^= x0;
    }
    x0 += ksc[(i+1)%3];
    x1 += ksc[(i+2)%3] + (unsigned)(i+1);
  }
  unsigned bits = x0 ^ x1;
  float u = __uint_as_float((bits >> 9) | 0x3F800000u) - 1.0f;
  u = fmaxf(u, 1.17549435e-38f);
  return -logf(-logf(u));
}

__device__ inline float sigf(float x){ return 1.0f/(1.0f + expf(-x)); }

// ---------------- wave-parallel 256-flag poll ----------------
// One wave (64 lanes x 4 flags) polls all 256 per-block flags (64B-strided,
// monotone). Divergent lanes idle in exec-off state until all satisfied.
__device__ inline void poll256(unsigned* flags, unsigned tgt){
  const int l = threadIdx.x & 63;
  #pragma unroll
  for (int j = 0; j < 4; ++j){
    while (__hip_atomic_load(&flags[(l*4 + j)*16], RLX, AGENT) < tgt){
      __builtin_amdgcn_s_sleep(1);
    }
  }
}

// ---------------- block reductions (verbatim R8) ----------------
__device__ inline float blk_red_max(float v, float* scr){
  #pragma unroll
  for (int m = 1; m < 64; m <<= 1) v = fmaxf(v, __shfl_xor(v, m, 64));
  if ((threadIdx.x & 63) == 0) scr[threadIdx.x >> 6] = v;
  __syncthreads();
  float r = scr[0];
  #pragma unroll
  for (int i = 1; i < 8; ++i) r = fmaxf(r, scr[i]);
  __syncthreads();
  return r;
}
__device__ inline float blk_red_sum(float v, float* scr){
  #pragma unroll
  for (int m = 1; m < 64; m <<= 1) v += __shfl_xor(v, m, 64);
  if ((threadIdx.x & 63) == 0) scr[threadIdx.x >> 6] = v;
  __syncthreads();
  float r = 0.f;
  #pragma unroll
  for (int i = 0; i < 8; ++i) r += scr[i];
  __syncthreads();
  return r;
}

// ---------------- precompute kernels (verbatim R8) -----------
__global__ void k_msum_part(const float* __restrict__ emb, const int* __restrict__ lens,
                            float* __restrict__ part){
  int blk = blockIdx.x, b = blk >> 3, lc = blk & 7;
  int len = lens[b];
  int l0 = lc*64, l1 = len < l0+64 ? len : l0+64;
  for (int h = threadIdx.x; h < 512; h += 256){
    float a = 0.f;
    for (int l = l0; l < l1; ++l) a += emb[(b*512 + l)*512 + h];
    part[blk*512 + h] = a;
  }
}
__global__ void k_msum(const float* __restrict__ part, float* __restrict__ msumT){
  int b = blockIdx.x;
  for (int h = threadIdx.x; h < 512; h += 256){
    float a = 0.f;
    #pragma unroll
    for (int lc = 0; lc < 8; ++lc) a += part[(b*8+lc)*512 + h];
    msumT[h*64 + b] = a;
  }
}
__global__ void k_kv(const float* __restrict__ msumT,
                     const float* __restrict__ kw, const float* __restrict__ kb,
                     const float* __restrict__ vw, const float* __restrict__ vb,
                     float* __restrict__ keysum, float* __restrict__ valsum){
  int which = blockIdx.x >> 7;
  int i = ((blockIdx.x & 127) << 2) + (threadIdx.x >> 6);
  int b = threadIdx.x & 63;
  const float* W = which ? vw : kw;
  float a = 0.f;
  for (int h = 0; h < 512; ++h) a = fmaf(msumT[h*64+b], W[i*512+h], a);
  float bias = which ? vb[i] : kb[i];
  float* out = which ? valsum : keysum;
  out[b*512 + i] = a + 512.0f*bias;
}
__global__ void k_ceT(const float* __restrict__ ce, float* __restrict__ ceT){
  int idx = blockIdx.x*256 + threadIdx.x;
  if (idx < 32768){ int v = idx >> 9, e = idx & 511; ceT[e*64 + v] = ce[v*512 + e]; }
}
__global__ void k_tok(const float* __restrict__ ceT, const float* __restrict__ w_ih,
                      const float* __restrict__ b_ih, const float* __restrict__ b_hh,
                      float* __restrict__ tok){
  int idx = blockIdx.x*256 + threadIdx.x;
  int v = idx & 63, row = idx >> 6;
  float a = 0.f;
  for (int e = 0; e < 512; ++e) a = fmaf(ceT[e*64+v], w_ih[row*1024 + e], a);
  tok[v*2048 + row] = a + b_ih[row] + b_hh[row];
}
// cdnT transpose, x slot0 init (ctx0 = valsum/512, hh0 = 0), t=0 outputs, barrier zeroing
__global__ void k_init(const float* __restrict__ valsum, const float* __restrict__ cdn_w,
                       float* __restrict__ cdnT, float* __restrict__ xT,
                       float* __restrict__ out, unsigned* __restrict__ bar){
  int idx = blockIdx.x*256 + threadIdx.x;
  if (idx < 65536){
    int v = idx >> 10, k = idx & 1023;
    cdnT[k*64 + v] = cdn_w[idx];
  } else if (idx < 98304){
    int r = idx - 65536; int j = r >> 6, b = r & 63;
    xT[j*64 + b] = valsum[b*512 + j] * (1.0f/512.0f);
  } else if (idx < 131072){
    xT[idx - 65536] = 0.f;
  } else if (idx < 135168){
    int r = idx - 131072; int b = r >> 6, v = r & 63;
    out[b*12800 + v] = 0.f;
  } else if (idx < 135232){
    int b = idx - 135168;
    out[819200 + b*200] = 0.f;
  } else if (idx < 139392){
    bar[idx - 135232] = 0u;   // flags[256*16] region
  }
}

// ---------------- main persistent loop kernel ----------------
// R8 base (256 blocks x 512 thr, 2 cells/block, static LDS, explicit-softmax
// Phase B). FP sequence byte-identical to R8 (7 consecutive passing compiles).
// ONLY change: barrier waits are split per wave for pipeline overlap:
//  - wave 4 polls t1(s-1) (h-half final) -> releases waves 5-7 via LDS flag;
//    waves 4-7 (k>=512 = h rows only) load+compute during other blocks'
//    Phase B / barrier-2 window.
//  - wave 0 polls t2(s-1) (ctx final) -> releases waves 1-3 (ctx rows).
//  - B-blocks gate Phase B on t1(s) the same way (wave 4 polls).
// Overlap-safe: waves 4-7 read only rows >=512 while Phase B writes rows <512.
__global__ __launch_bounds__(GTHR, 2) void k_loop(
    const float* __restrict__ w_ih, const float* __restrict__ w_hh,
    const int* __restrict__ batch_y, const float* __restrict__ tok,
    const float* __restrict__ keysum, const float* __restrict__ valsum,
    const float* __restrict__ cdnT, const float* __restrict__ cdn_b,
    float* __restrict__ xT, float* __restrict__ out,
    unsigned* __restrict__ flags){
  __shared__ float W_lds[1024][8];     // [k][r], r = gate*2 + cell
  __shared__ float red[8][8][64];      // [wave][r][b]
  __shared__ float gates_lds[8][64];
  __shared__ float cc_lds[2][64];
  __shared__ float pb_h[512], pb_c[512];
  __shared__ float pb_lp[8][64];
  __shared__ float scr[8];
  __shared__ int done_h, done_c, done_pb;

  const int tid = threadIdx.x;
  const int blk = blockIdx.x;
  const bool HASB = (blk < 64);

  if (tid == 0){ done_h = 0; done_c = 0; done_pb = 0; }
  for (int idx = tid; idx < 8192; idx += GTHR){
    int k = idx >> 3, r = idx & 7;
    int g = r >> 1, c = r & 1;
    int row = g*512 + blk*2 + c;
    W_lds[k][r] = (k < 512) ? w_ih[row*1024 + 512 + k] : w_hh[row*512 + (k - 512)];
  }
  if (tid < 128) cc_lds[tid >> 6][tid & 63] = 0.0f;
  __syncthreads();

  const int w = tid >> 6, l = tid & 63, kg = l >> 4, bg = l & 15;
  const float SCALE = 22.627416997969522f;   // sqrt(512)

#define ISS1(R, JJ) do{ const float* _p = xin + (((kbase + (JJ)*4) << 6) | (bg << 2)); \
  asm volatile("global_load_dwordx4 %0, %1, off sc0 sc1" : "=v"(R) : "v"(_p)); }while(0)
#define ISS8(P, J0) do{ ISS1(P##0,(J0)+0);ISS1(P##1,(J0)+1);ISS1(P##2,(J0)+2);ISS1(P##3,(J0)+3); \
  ISS1(P##4,(J0)+4);ISS1(P##5,(J0)+5);ISS1(P##6,(J0)+6);ISS1(P##7,(J0)+7); }while(0)
#define CMP1(R, JJ) do{ int _k = kbase + (JJ)*4; \
  f4v _wA = *(const f4v*)&W_lds[_k][0]; f4v _wB = *(const f4v*)&W_lds[_k][4]; \
  float _wv[8] = {_wA.x,_wA.y,_wA.z,_wA.w,_wB.x,_wB.y,_wB.z,_wB.w}; \
  float _xv[4] = {R.x,R.y,R.z,R.w}; \
  _Pragma("unroll") for (int _r = 0; _r < 8; ++_r){ \
    _Pragma("unroll") for (int _q = 0; _q < 4; ++_q) \
      acc[_r][_q] = fmaf(_wv[_r], _xv[_q], acc[_r][_q]); } }while(0)
#define CMP8(P, J0) do{ CMP1(P##0,(J0)+0);CMP1(P##1,(J0)+1);CMP1(P##2,(J0)+2);CMP1(P##3,(J0)+3); \
  CMP1(P##4,(J0)+4);CMP1(P##5,(J0)+5);CMP1(P##6,(J0)+6);CMP1(P##7,(J0)+7); }while(0)
#define WAITV(N) do{ asm volatile("s_waitcnt vmcnt(" #N ")" ::: "memory"); \
  __builtin_amdgcn_sched_barrier(0); }while(0)

  for (int s = 0; s < NSTEP; ++s){
    const float* xin  = xT + (size_t)(s & 1)*65536;
    float*       xout = xT + (size_t)((s + 1) & 1)*65536;
    const unsigned t1 = (unsigned)(2*s + 1), t2 = (unsigned)(2*s + 2);
    const unsigned tgt_h = (s == 0) ? 0u : (unsigned)(2*s - 1);
    const unsigned tgt_c = (s == 0) ? 0u : (unsigned)(2*s);

    // ---- per-wave input gating ----
    if (w >= 4){
      // h rows (k>=512): final once t1(s-1) passed
      if (w == 4){
        poll256(flags, tgt_h);
        __hip_atomic_store(&done_h, s + 1, RLX, WGRP);
      } else {
        while (__hip_atomic_load(&done_h, RLX, WGRP) < s + 1){
          __builtin_amdgcn_s_sleep(1);
        }
      }
    } else {
      // ctx rows (k<512): final once t2(s-1) passed
      if (w == 0){
        poll256(flags, tgt_c);
        __hip_atomic_store(&done_c, s + 1, RLX, WGRP);
      } else {
        while (__hip_atomic_load(&done_c, RLX, WGRP) < s + 1){
          __builtin_amdgcn_s_sleep(1);
        }
      }
    }

    // prefetch token-gate value (L2-hot normal loads) — verbatim R8
    const int rr = tid >> 6, rb = tid & 63;
    int yprev = (s == 0) ? 0 : batch_y[rb*200 + s];
    float tokval = tok[yprev*2048 + (rr >> 1)*512 + blk*2 + (rr & 1)];

    // ---- Phase A: gates via counted-vmcnt pipelined sc1 loads (verbatim R8) ----
    float acc[8][4];
    #pragma unroll
    for (int r = 0; r < 8; ++r)
      #pragma unroll
      for (int q = 0; q < 4; ++q) acc[r][q] = 0.f;

    const int kbase = w*128 + kg;
    {
      f4v A0,A1,A2,A3,A4,A5,A6,A7,B0,B1,B2,B3,B4,B5,B6,B7;
      ISS8(A, 0);
      ISS8(B, 8);
      WAITV(8); CMP8(A, 0);
      ISS8(A, 16);
      WAITV(8); CMP8(B, 8);
      ISS8(B, 24);
      WAITV(8); CMP8(A, 16);
      WAITV(0); CMP8(B, 24);
    }

    // reduce across kg (lanes ^16, ^32) — verbatim R8
    #pragma unroll
    for (int r = 0; r < 8; ++r)
      #pragma unroll
      for (int q = 0; q < 4; ++q){
        float v = acc[r][q];
        v += __shfl_xor(v, 16, 64);
        v += __shfl_xor(v, 32, 64);
        acc[r][q] = v;
      }
    if (l < 16){
      #pragma unroll
      for (int r = 0; r < 8; ++r)
        *(float4*)&red[w][r][bg*4] = make_float4(acc[r][0], acc[r][1], acc[r][2], acc[r][3]);
    }
    __syncthreads();
    {
      float g = 0.f;
      #pragma unroll
      for (int ww = 0; ww < 8; ++ww) g += red[ww][rr][rb];
      gates_lds[rr][rb] = g + tokval;
    }
    __syncthreads();
    if (tid < 128){
      int c = tid >> 6, b = tid & 63;
      float ig = gates_lds[0 + c][b];
      float fg = gates_lds[2 + c][b];
      float gg = gates_lds[4 + c][b];
      float og = gates_lds[6 + c][b];
      float cprev = cc_lds[c][b];
      float cnew = sigf(fg)*cprev + sigf(ig)*tanhf(gg);
      float hnew = sigf(og)*tanhf(cnew);
      cc_lds[c][b] = cnew;
      float oldh = __hip_atomic_exchange(&xout[(512 + blk*2 + c)*64 + b], hnew, RLX, AGENT);
      asm volatile("" :: "v"(oldh));
    }

    // ---- barrier-1 arrival (non-B blocks arrive t2 directly) ----
    asm volatile("s_waitcnt vmcnt(0)" ::: "memory");
    __syncthreads();
    if (tid == 0){
      unsigned o = __hip_atomic_exchange(&flags[blk*16], HASB ? t1 : t2, RLX, AGENT);
      asm volatile("" :: "v"(o));
    }

    if (HASB){
      // gate Phase B on t1(s) globally: wave 4 polls, others LDS-spin
      if (w == 4){
        poll256(flags, t1);
        __hip_atomic_store(&done_pb, s + 1, RLX, WGRP);
      } else {
        while (__hip_atomic_load(&done_pb, RLX, WGRP) < s + 1){
          __builtin_amdgcn_s_sleep(1);
        }
      }

      // ---- Phase B: attend + logits + sampling (verbatim R8) ----
      int b = blk;
      int jj = tid;
      float h = __hip_atomic_load(&xout[(512 + jj)*64 + b], RLX, AGENT);
      pb_h[jj] = h;
      float sc = (keysum[b*512 + jj] * h) / SCALE;
      float m = blk_red_max(sc, scr);
      float e = expf(sc - m);
      float S = blk_red_sum(e, scr);
      float cx = valsum[b*512 + jj] * (e / S);
      pb_c[jj] = cx;
      float oldc = __hip_atomic_exchange(&xout[jj*64 + b], cx, RLX, AGENT);
      asm volatile("" :: "v"(oldc));
      __syncthreads();
      int kq = tid >> 6, v = tid & 63;
      float part = 0.f;
      for (int k = kq*128; k < kq*128 + 128; ++k){
        float xh = (k < 512) ? pb_h[k] : pb_c[k - 512];
        part = fmaf(cdnT[k*64 + v], xh, part);
      }
      pb_lp[kq][v] = part;
      __syncthreads();
      if (tid < 64){
        int v2 = tid;
        float logit = cdn_b[v2];
        #pragma unroll
        for (int q = 0; q < 8; ++q) logit += pb_lp[q][v2];
        out[b*12800 + (s+1)*64 + v2] = logit;
        float z = gumbel_tf((unsigned)((b*199 + s)*64 + v2)) + logit;
        int idx = v2;
        #pragma unroll
        for (int mm = 1; mm < 64; mm <<= 1){
          float oz = __shfl_xor(z, mm, 64);
          int   oi = __shfl_xor(idx, mm, 64);
          if (oz > z || (oz == z && oi < idx)){ z = oz; idx = oi; }
        }
        if (v2 == 0) out[819200 + b*200 + (s+1)] = (float)idx;
      }

      // barrier-2 arrival for B-blocks
      asm volatile("s_waitcnt vmcnt(0)" ::: "memory");
      __syncthreads();
      if (tid == 0){
        unsigned o = __hip_atomic_exchange(&flags[blk*16], t2, RLX, AGENT);
        asm volatile("" :: "v"(o));
      }
    }
    // no trailing grid-wide wait: next iteration's per-wave gates handle it
  }
#undef ISS1
#undef ISS8
#undef CMP1
#undef CMP8
#undef WAITV
}

// ---------------- launcher ----------------
extern "C" void kernel_launch(void* const* d_in, const int* in_sizes, int n_in,
                              void* d_out, int out_size, void* d_ws, size_t ws_size,
                              hipStream_t stream){
  const float* seq     = (const float*)d_in[0];
  const float* key_w   = (const float*)d_in[1];
  const float* key_b   = (const float*)d_in[2];
  const float* value_w = (const float*)d_in[3];
  const float* value_b = (const float*)d_in[4];
  const float* char_e  = (const float*)d_in[5];
  const float* w_ih    = (const float*)d_in[6];
  const float* w_hh    = (const float*)d_in[7];
  const float* b_ih    = (const float*)d_in[8];
  const float* b_hh    = (const float*)d_in[9];
  const float* cdn_w   = (const float*)d_in[10];
  const float* cdn_b   = (const float*)d_in[11];
  const int*   lens    = (const int*)d_in[12];
  const int*   batch_y = (const int*)d_in[13];
  float* out = (float*)d_out;
  float* ws  = (float*)d_ws;

  float* msum_part = ws;              // 262144 (precompute only)
  float* msumT     = ws + 262144;     // 32768   [h][b]
  float* keysum    = ws + 294912;     // 32768   [b][i]
  float* valsum    = ws + 327680;     // 32768   [b][i]
  float* tok       = ws + 360448;     // 131072  [v][row]
  float* cdnT      = ws + 491520;     // 65536   [k][v]
  float* ceT       = ws + 557056;     // 32768   [e][v]
  float* xT        = ws + 589824;     // 131072  2 x [k][b] ping-pong
  unsigned* bar    = (unsigned*)(ws + 720896); // flags[256*16]

  k_msum_part<<<512, 256, 0, stream>>>(seq, lens, msum_part);
  k_msum     <<<64,  256, 0, stream>>>(msum_part, msumT);
  k_kv       <<<256, 256, 0, stream>>>(msumT, key_w, key_b, value_w, value_b, keysum, valsum);
  k_ceT      <<<128, 256, 0, stream>>>(char_e, ceT);
  k_tok      <<<512, 256, 0, stream>>>(ceT, w_ih, b_ih, b_hh, tok);
  k_init     <<<545, 256, 0, stream>>>(valsum, cdn_w, cdnT, xT, out, bar);

  k_loop<<<GBLK, GTHR, 0, stream>>>(w_ih, w_hh, batch_y, tok, keysum, valsum,
                                    cdnT, cdn_b, xT, out, bar);
  (void)in_sizes; (void)n_in; (void)out_size; (void)ws_size;
}